// Round 6
// baseline (46.949 us; speedup 1.0000x reference)
//
#include <hip/hip_runtime.h>
#include <math.h>

#define BS 256            // block size
#define NBLK 1024         // big-kernel grid
#define NWAVES (BS / 64)
#define NSLOT 64          // spread join slots (one 128-B line each)
#define PER_SLOT (NBLK / NSLOT)   // 16 arrivals per slot
#define FXS 4294967296.0  // 2^32 fixed-point scale (deterministic integer join)

// ws layout (bytes):
//   [0,     8192)  double bsum[1024]   stats partials (plain stores, no init needed)
//   [8192, 16384)  double bss[1024]
//   [16384,20480)  float  bmn[1024]
//   [20480,24576)  float  bmx[1024]
//   [24576,32768)  int64 loss slot i at 24576 + i*128   (zeroed by k_stats blk 0)
//   [32768,40960)  u32   cnt  slot i at 32768 + i*128   (zeroed by k_stats blk 0)

// ---------- wave reduction helpers ----------
__device__ inline double wred_sum(double v) {
#pragma unroll
    for (int o = 32; o > 0; o >>= 1) v += __shfl_down(v, o, 64);
    return v;
}
__device__ inline float wred_min(float v) {
#pragma unroll
    for (int o = 32; o > 0; o >>= 1) v = fminf(v, __shfl_down(v, o, 64));
    return v;
}
__device__ inline float wred_max(float v) {
#pragma unroll
    for (int o = 32; o > 0; o >>= 1) v = fmaxf(v, __shfl_down(v, o, 64));
    return v;
}

__device__ inline void acc_stats(float4 v, double& s, double& ss, float& mn, float& mx) {
    mn = fminf(mn, fminf(fminf(v.x, v.y), fminf(v.z, v.w)));
    mx = fmaxf(mx, fmaxf(fmaxf(v.x, v.y), fmaxf(v.z, v.w)));
    s += (double)v.x + (double)v.y + (double)v.z + (double)v.w;
    ss += (double)v.x * v.x + (double)v.y * v.y
        + (double)v.z * v.z + (double)v.w * v.w;
}

// ---------- pass 1: per-block {sum, sumsq, min, max} over targets ----------
__global__ void __launch_bounds__(BS) k_stats(
        const float* __restrict__ t, int n,
        double* __restrict__ bsum, double* __restrict__ bss,
        float* __restrict__ bmn, float* __restrict__ bmx,
        char* __restrict__ slots) {
    // block 0 zeroes the join slots (plain stores; dispatch boundary publishes)
    if (blockIdx.x == 0) {
        if (threadIdx.x < NSLOT)
            *(long long*)(slots + (size_t)threadIdx.x * 128) = 0ll;
        else if (threadIdx.x < 2 * NSLOT)
            *(unsigned*)(slots + 8192 + (size_t)(threadIdx.x - NSLOT) * 128) = 0u;
    }

    int tid = blockIdx.x * BS + threadIdx.x;
    const int stride = NBLK * BS;
    int n4 = n >> 2;
    const float4* t4 = (const float4*)t;

    double s = 0.0, ss = 0.0;
    float mn = 3.4e38f, mx = -3.4e38f;
    int i = tid;
    for (; i + 3 * stride < n4; i += 4 * stride) {   // 4 loads in flight
        float4 a = t4[i];
        float4 b = t4[i + stride];
        float4 c = t4[i + 2 * stride];
        float4 d = t4[i + 3 * stride];
        acc_stats(a, s, ss, mn, mx);
        acc_stats(b, s, ss, mn, mx);
        acc_stats(c, s, ss, mn, mx);
        acc_stats(d, s, ss, mn, mx);
    }
    for (; i < n4; i += stride) {
        float4 a = t4[i];
        acc_stats(a, s, ss, mn, mx);
    }
    if (tid == 0) {  // scalar tail (n % 4), robustness only
        for (int j = (n4 << 2); j < n; j++) {
            float v = t[j];
            mn = fminf(mn, v); mx = fmaxf(mx, v);
            s += v; ss += (double)v * v;
        }
    }

    s = wred_sum(s); ss = wred_sum(ss); mn = wred_min(mn); mx = wred_max(mx);

    __shared__ double sh_s[NWAVES], sh_ss[NWAVES];
    __shared__ float sh_mn[NWAVES], sh_mx[NWAVES];
    int wid = threadIdx.x >> 6, lane = threadIdx.x & 63;
    if (lane == 0) { sh_s[wid] = s; sh_ss[wid] = ss; sh_mn[wid] = mn; sh_mx[wid] = mx; }
    __syncthreads();
    if (threadIdx.x == 0) {
        double S = sh_s[0], SS = sh_ss[0];
        float MN = sh_mn[0], MX = sh_mx[0];
        for (int k = 1; k < NWAVES; k++) {
            S += sh_s[k]; SS += sh_ss[k];
            MN = fminf(MN, sh_mn[k]); MX = fmaxf(MX, sh_mx[k]);
        }
        bsum[blockIdx.x] = S; bss[blockIdx.x] = SS;
        bmn[blockIdx.x] = MN; bmx[blockIdx.x] = MX;
    }
}

// ---------- pass 2: redundant stats fold + weighted L1 + spread-slot join ----------
__device__ inline float welem(float g, float x, float gmin, float m1, float m2,
                              float sl, float sm, float shv) {
    float w = (g <= m1) ? (g - gmin) * sl
            : (g <= m2) ? (g - m1) * sm + 0.2f
                        : (g - m2) * shv + 0.7f;
    return fabsf(g - x) * w;
}

__global__ void __launch_bounds__(BS) k_loss(
        const float* __restrict__ x, const float* __restrict__ t, int n,
        const double* __restrict__ sbsum, const double* __restrict__ sbss,
        const float* __restrict__ sbmn, const float* __restrict__ sbmx,
        char* __restrict__ slots, float* __restrict__ out) {
    // --- redundant stats fold: 1024 partials, identical order in every block ---
    __shared__ double sh_s[NWAVES], sh_ss[NWAVES];
    __shared__ float sh_mn[NWAVES], sh_mx[NWAVES];
    __shared__ float s_c[8];
    {
        double s = 0.0, ss = 0.0;
        float mn = 3.4e38f, mx = -3.4e38f;
#pragma unroll 4
        for (int i = threadIdx.x; i < NBLK; i += BS) {
            s += sbsum[i]; ss += sbss[i];
            mn = fminf(mn, sbmn[i]); mx = fmaxf(mx, sbmx[i]);
        }
        s = wred_sum(s); ss = wred_sum(ss); mn = wred_min(mn); mx = wred_max(mx);
        int wid = threadIdx.x >> 6, lane = threadIdx.x & 63;
        if (lane == 0) { sh_s[wid] = s; sh_ss[wid] = ss; sh_mn[wid] = mn; sh_mx[wid] = mx; }
        __syncthreads();
        if (threadIdx.x == 0) {
            double S = sh_s[0], SS = sh_ss[0];
            float MN = sh_mn[0], MX = sh_mx[0];
            for (int k = 1; k < NWAVES; k++) {
                S += sh_s[k]; SS += sh_ss[k];
                MN = fminf(MN, sh_mn[k]); MX = fmaxf(MX, sh_mx[k]);
            }
            double dn = (double)n;
            double mean = S / dn;
            double var = (SS - S * S / dn) / (dn - 1.0);   // ddof=1
            double sd = sqrt(var);
            float m1 = (float)(mean + sd);
            float m2 = (float)(mean + 3.0 * sd);
            s_c[0] = MN;                  // gmin
            s_c[1] = m1;
            s_c[2] = m2;
            s_c[3] = 0.2f / (m1 - MN);    // low slope
            s_c[4] = 0.5f / (m2 - m1);    // mid slope
            s_c[5] = 0.3f / (MX - m2);    // high slope
        }
        __syncthreads();
    }
    float gmin = s_c[0], m1 = s_c[1], m2 = s_c[2];
    float sl = s_c[3], sm = s_c[4], shv = s_c[5];

    int tid = blockIdx.x * BS + threadIdx.x;
    const int stride = NBLK * BS;
    int n4 = n >> 2;
    const float4* x4 = (const float4*)x;
    const float4* t4 = (const float4*)t;

    double acc = 0.0;
    int i = tid;
    for (; i + 3 * stride < n4; i += 4 * stride) {   // 8 loads in flight
        float4 t0 = t4[i];
        float4 t1 = t4[i + stride];
        float4 t2 = t4[i + 2 * stride];
        float4 t3 = t4[i + 3 * stride];
        float4 x0 = x4[i];
        float4 x1 = x4[i + stride];
        float4 x2 = x4[i + 2 * stride];
        float4 x3 = x4[i + 3 * stride];
        float e0 = welem(t0.x, x0.x, gmin, m1, m2, sl, sm, shv)
                 + welem(t0.y, x0.y, gmin, m1, m2, sl, sm, shv)
                 + welem(t0.z, x0.z, gmin, m1, m2, sl, sm, shv)
                 + welem(t0.w, x0.w, gmin, m1, m2, sl, sm, shv);
        float e1 = welem(t1.x, x1.x, gmin, m1, m2, sl, sm, shv)
                 + welem(t1.y, x1.y, gmin, m1, m2, sl, sm, shv)
                 + welem(t1.z, x1.z, gmin, m1, m2, sl, sm, shv)
                 + welem(t1.w, x1.w, gmin, m1, m2, sl, sm, shv);
        float e2 = welem(t2.x, x2.x, gmin, m1, m2, sl, sm, shv)
                 + welem(t2.y, x2.y, gmin, m1, m2, sl, sm, shv)
                 + welem(t2.z, x2.z, gmin, m1, m2, sl, sm, shv)
                 + welem(t2.w, x2.w, gmin, m1, m2, sl, sm, shv);
        float e3 = welem(t3.x, x3.x, gmin, m1, m2, sl, sm, shv)
                 + welem(t3.y, x3.y, gmin, m1, m2, sl, sm, shv)
                 + welem(t3.z, x3.z, gmin, m1, m2, sl, sm, shv)
                 + welem(t3.w, x3.w, gmin, m1, m2, sl, sm, shv);
        acc += (double)e0 + (double)e1 + (double)e2 + (double)e3;
    }
    for (; i < n4; i += stride) {
        float4 tv = t4[i], xv = x4[i];
        float e0 = welem(tv.x, xv.x, gmin, m1, m2, sl, sm, shv)
                 + welem(tv.y, xv.y, gmin, m1, m2, sl, sm, shv)
                 + welem(tv.z, xv.z, gmin, m1, m2, sl, sm, shv)
                 + welem(tv.w, xv.w, gmin, m1, m2, sl, sm, shv);
        acc += (double)e0;
    }
    if (tid == 0) {  // scalar tail
        for (int j = (n4 << 2); j < n; j++)
            acc += (double)welem(t[j], x[j], gmin, m1, m2, sl, sm, shv);
    }

    acc = wred_sum(acc);
    __shared__ double sh_acc[NWAVES];
    __shared__ int s_fin;
    int wid = threadIdx.x >> 6, lane = threadIdx.x & 63;
    if (lane == 0) sh_acc[wid] = acc;
    __syncthreads();
    if (threadIdx.x == 0) {
        double S = sh_acc[0];
        for (int k = 1; k < NWAVES; k++) S += sh_acc[k];
        int slot = blockIdx.x & (NSLOT - 1);
        long long* lslot = (long long*)(slots + (size_t)slot * 128);
        unsigned*  cslot = (unsigned*)(slots + 8192 + (size_t)slot * 128);
        // value travels THROUGH a relaxed agent-scope atomic (coherent point)
        __hip_atomic_fetch_add(lslot, (long long)llrint(S * FXS),
                               __ATOMIC_RELAXED, __HIP_MEMORY_SCOPE_AGENT);
        // ensure the value RMW is committed before arriving
        asm volatile("s_waitcnt vmcnt(0)" ::: "memory");
        unsigned prev = __hip_atomic_fetch_add(cslot, 1u,
                               __ATOMIC_RELAXED, __HIP_MEMORY_SCOPE_AGENT);
        s_fin = (prev == PER_SLOT - 1) ? 1 : 0;   // this block filled its slot
    }
    __syncthreads();
    if (!s_fin) return;

    // ---- slot-filling blocks (64 of them) spin until all arrived, then all
    // compute the identical final value (benign redundant writes). ----
    if (threadIdx.x < 64) {
        unsigned total;
        do {
            unsigned c = __hip_atomic_load(
                (unsigned*)(slots + 8192 + (size_t)threadIdx.x * 128),
                __ATOMIC_RELAXED, __HIP_MEMORY_SCOPE_AGENT);
#pragma unroll
            for (int o = 32; o > 0; o >>= 1) c += __shfl_down(c, o, 64);
            total = __shfl(c, 0, 64);
            if (total != NBLK) __builtin_amdgcn_s_sleep(32);
        } while (total != NBLK);
        long long v = __hip_atomic_load(
            (long long*)(slots + (size_t)threadIdx.x * 128),
            __ATOMIC_RELAXED, __HIP_MEMORY_SCOPE_AGENT);
#pragma unroll
        for (int o = 32; o > 0; o >>= 1) v += __shfl_down(v, o, 64);
        if (threadIdx.x == 0)
            out[0] = (float)(((double)v / FXS) / (double)n);
    }
}

extern "C" void kernel_launch(void* const* d_in, const int* in_sizes, int n_in,
                              void* d_out, int out_size, void* d_ws, size_t ws_size,
                              hipStream_t stream) {
    const float* inp = (const float*)d_in[0];
    const float* tgt = (const float*)d_in[1];
    int n = in_sizes[0];

    char* ws = (char*)d_ws;
    double* bsum = (double*)(ws);
    double* bss  = (double*)(ws + 8192);
    float*  bmn  = (float*)(ws + 16384);
    float*  bmx  = (float*)(ws + 20480);
    char*   slots = ws + 24576;   // [0,8192): loss slots, [8192,16384): counters

    k_stats<<<NBLK, BS, 0, stream>>>(tgt, n, bsum, bss, bmn, bmx, slots);
    k_loss<<<NBLK, BS, 0, stream>>>(inp, tgt, n, bsum, bss, bmn, bmx,
                                    slots, (float*)d_out);
}

// Round 7
// 45.490 us; speedup vs baseline: 1.0321x; 1.0321x over previous
//
#include <hip/hip_runtime.h>
#include <math.h>

#define BS 256          // big-kernel block size
#define NB 2048         // big-kernel grid (8 blocks/CU on 256 CUs)
#define NWAVES (BS / 64)
#define TBS 1024        // fold-kernel block size
#define TNW (TBS / 64)

// ---------- wave reduction helpers ----------
__device__ inline double wred_sum(double v) {
#pragma unroll
    for (int o = 32; o > 0; o >>= 1) v += __shfl_down(v, o, 64);
    return v;
}
__device__ inline float wred_min(float v) {
#pragma unroll
    for (int o = 32; o > 0; o >>= 1) v = fminf(v, __shfl_down(v, o, 64));
    return v;
}
__device__ inline float wred_max(float v) {
#pragma unroll
    for (int o = 32; o > 0; o >>= 1) v = fmaxf(v, __shfl_down(v, o, 64));
    return v;
}

__device__ inline void acc_stats(float4 v, double& s, double& ss, float& mn, float& mx) {
    mn = fminf(mn, fminf(fminf(v.x, v.y), fminf(v.z, v.w)));
    mx = fmaxf(mx, fmaxf(fmaxf(v.x, v.y), fmaxf(v.z, v.w)));
    s += (double)v.x + (double)v.y + (double)v.z + (double)v.w;
    ss += (double)v.x * v.x + (double)v.y * v.y
        + (double)v.z * v.z + (double)v.w * v.w;
}

// ---------- pass 1: per-block {sum, sumsq, min, max} over targets ----------
// Plain scattered stores; coherence comes from the dispatch boundary.
__global__ void __launch_bounds__(BS) k_stats(
        const float* __restrict__ t, int n,
        double* __restrict__ bsum, double* __restrict__ bss,
        float* __restrict__ bmn, float* __restrict__ bmx) {
    int tid = blockIdx.x * BS + threadIdx.x;
    const int stride = NB * BS;
    int n4 = n >> 2;
    const float4* t4 = (const float4*)t;

    double s = 0.0, ss = 0.0;
    float mn = 3.4e38f, mx = -3.4e38f;
    int i = tid;
    for (; i + 3 * stride < n4; i += 4 * stride) {   // 4 loads in flight
        float4 a = t4[i];
        float4 b = t4[i + stride];
        float4 c = t4[i + 2 * stride];
        float4 d = t4[i + 3 * stride];
        acc_stats(a, s, ss, mn, mx);
        acc_stats(b, s, ss, mn, mx);
        acc_stats(c, s, ss, mn, mx);
        acc_stats(d, s, ss, mn, mx);
    }
    for (; i < n4; i += stride) {
        float4 a = t4[i];
        acc_stats(a, s, ss, mn, mx);
    }
    if (tid == 0) {  // scalar tail (n % 4), robustness only
        for (int j = (n4 << 2); j < n; j++) {
            float v = t[j];
            mn = fminf(mn, v); mx = fmaxf(mx, v);
            s += v; ss += (double)v * v;
        }
    }

    s = wred_sum(s); ss = wred_sum(ss); mn = wred_min(mn); mx = wred_max(mx);

    __shared__ double sh_s[NWAVES], sh_ss[NWAVES];
    __shared__ float sh_mn[NWAVES], sh_mx[NWAVES];
    int wid = threadIdx.x >> 6, lane = threadIdx.x & 63;
    if (lane == 0) { sh_s[wid] = s; sh_ss[wid] = ss; sh_mn[wid] = mn; sh_mx[wid] = mx; }
    __syncthreads();
    if (threadIdx.x == 0) {
        double S = sh_s[0], SS = sh_ss[0];
        float MN = sh_mn[0], MX = sh_mx[0];
        for (int k = 1; k < NWAVES; k++) {
            S += sh_s[k]; SS += sh_ss[k];
            MN = fminf(MN, sh_mn[k]); MX = fmaxf(MX, sh_mx[k]);
        }
        bsum[blockIdx.x] = S; bss[blockIdx.x] = SS;
        bmn[blockIdx.x] = MN; bmx[blockIdx.x] = MX;
    }
}

// ---------- pass 2: fold block partials -> piecewise-weight constants ----------
__global__ void __launch_bounds__(TBS) k_finalize_stats(
        const double* __restrict__ bsum, const double* __restrict__ bss,
        const float* __restrict__ bmn, const float* __restrict__ bmx,
        long long n, float* __restrict__ stats) {
    double s = 0.0, ss = 0.0;
    float mn = 3.4e38f, mx = -3.4e38f;
    for (int i = threadIdx.x; i < NB; i += TBS) {
        s += bsum[i]; ss += bss[i];
        mn = fminf(mn, bmn[i]); mx = fmaxf(mx, bmx[i]);
    }
    s = wred_sum(s); ss = wred_sum(ss); mn = wred_min(mn); mx = wred_max(mx);

    __shared__ double sh_s[TNW], sh_ss[TNW];
    __shared__ float sh_mn[TNW], sh_mx[TNW];
    int wid = threadIdx.x >> 6, lane = threadIdx.x & 63;
    if (lane == 0) { sh_s[wid] = s; sh_ss[wid] = ss; sh_mn[wid] = mn; sh_mx[wid] = mx; }
    __syncthreads();
    if (threadIdx.x == 0) {
        double S = sh_s[0], SS = sh_ss[0];
        float MN = sh_mn[0], MX = sh_mx[0];
        for (int i = 1; i < TNW; i++) {
            S += sh_s[i]; SS += sh_ss[i];
            MN = fminf(MN, sh_mn[i]); MX = fmaxf(MX, sh_mx[i]);
        }
        double dn = (double)n;
        double mean = S / dn;
        double var = (SS - S * S / dn) / (dn - 1.0);   // ddof=1
        double sd = sqrt(var);
        float gmin = MN, gmax = MX;
        float m1 = (float)(mean + sd);
        float m2 = (float)(mean + 3.0 * sd);
        stats[0] = gmin;
        stats[1] = m1;
        stats[2] = m2;
        stats[3] = gmax;
        stats[4] = 0.2f / (m1 - gmin);   // low slope
        stats[5] = 0.5f / (m2 - m1);     // mid slope
        stats[6] = 0.3f / (gmax - m2);   // high slope
    }
}

// ---------- pass 3: weighted L1 partial sums (register-pipelined) ----------
__device__ inline float welem(float g, float x, float gmin, float m1, float m2,
                              float sl, float sm, float shv) {
    float w = (g <= m1) ? (g - gmin) * sl
            : (g <= m2) ? (g - m1) * sm + 0.2f
                        : (g - m2) * shv + 0.7f;
    return fabsf(g - x) * w;
}

__device__ inline float wquad(float4 tv, float4 xv, float gmin, float m1,
                              float m2, float sl, float sm, float shv) {
    return welem(tv.x, xv.x, gmin, m1, m2, sl, sm, shv)
         + welem(tv.y, xv.y, gmin, m1, m2, sl, sm, shv)
         + welem(tv.z, xv.z, gmin, m1, m2, sl, sm, shv)
         + welem(tv.w, xv.w, gmin, m1, m2, sl, sm, shv);
}

__global__ void __launch_bounds__(BS) k_loss(
        const float* __restrict__ x, const float* __restrict__ t, int n,
        const float* __restrict__ stats, double* __restrict__ bsum) {
    float gmin = stats[0], m1 = stats[1], m2 = stats[2];
    float sl = stats[4], sm = stats[5], shv = stats[6];
    int tid = blockIdx.x * BS + threadIdx.x;
    const int stride = NB * BS;
    int n4 = n >> 2;
    const float4* x4 = (const float4*)x;
    const float4* t4 = (const float4*)t;

    // nfull: uniform per-thread iteration count (16.7M/4/524288 = 8)
    int nfull = n4 / stride;
    int nmain = nfull & ~1;          // even part, pipelined 2 at a time
    double acc = 0.0;

    if (nmain >= 2) {
        // prologue: first pair in flight
        float4 ta = t4[tid],           xa = x4[tid];
        float4 tb = t4[tid + stride],  xb = x4[tid + stride];
        int i = tid + 2 * stride;
        for (int k = 2; k < nmain; k += 2, i += 2 * stride) {
            // prefetch next pair (4 loads issued before any consumption)
            float4 tc = t4[i],          xc = x4[i];
            float4 td = t4[i + stride], xd = x4[i + stride];
            // consume current pair
            float e = wquad(ta, xa, gmin, m1, m2, sl, sm, shv);
            float f = wquad(tb, xb, gmin, m1, m2, sl, sm, shv);
            acc += (double)e + (double)f;
            ta = tc; xa = xc; tb = td; xb = xd;
        }
        // epilogue
        float e = wquad(ta, xa, gmin, m1, m2, sl, sm, shv);
        float f = wquad(tb, xb, gmin, m1, m2, sl, sm, shv);
        acc += (double)e + (double)f;
    }
    // leftover full iterations (odd nfull) + ragged end
    for (int i = tid + nmain * stride; i < n4; i += stride) {
        float4 tv = t4[i], xv = x4[i];
        acc += (double)wquad(tv, xv, gmin, m1, m2, sl, sm, shv);
    }
    if (tid == 0) {  // scalar tail (n % 4)
        for (int j = (n4 << 2); j < n; j++)
            acc += (double)welem(t[j], x[j], gmin, m1, m2, sl, sm, shv);
    }

    acc = wred_sum(acc);
    __shared__ double sh_s[NWAVES];
    int wid = threadIdx.x >> 6, lane = threadIdx.x & 63;
    if (lane == 0) sh_s[wid] = acc;
    __syncthreads();
    if (threadIdx.x == 0) {
        double S = sh_s[0];
        for (int k = 1; k < NWAVES; k++) S += sh_s[k];
        bsum[blockIdx.x] = S;
    }
}

// ---------- pass 4: final mean ----------
__global__ void __launch_bounds__(TBS) k_final(
        const double* __restrict__ bsum, long long n, float* __restrict__ out) {
    double s = 0.0;
    for (int i = threadIdx.x; i < NB; i += TBS) s += bsum[i];
    s = wred_sum(s);
    __shared__ double sh_s[TNW];
    int wid = threadIdx.x >> 6, lane = threadIdx.x & 63;
    if (lane == 0) sh_s[wid] = s;
    __syncthreads();
    if (threadIdx.x == 0) {
        double S = sh_s[0];
        for (int i = 1; i < TNW; i++) S += sh_s[i];
        out[0] = (float)(S / (double)n);
    }
}

extern "C" void kernel_launch(void* const* d_in, const int* in_sizes, int n_in,
                              void* d_out, int out_size, void* d_ws, size_t ws_size,
                              hipStream_t stream) {
    const float* inp = (const float*)d_in[0];
    const float* tgt = (const float*)d_in[1];
    int n = in_sizes[0];

    // workspace layout (bytes); plain stores -> no init needed:
    //   [0,      16384) double sum1[NB]
    //   [16384,  32768) double ss1[NB]
    //   [32768,  40960) float  mn1[NB]
    //   [40960,  49152) float  mx1[NB]
    //   [49152,  49216) float  stats[16]
    //   [49280,  65664) double sum2[NB]
    char* ws = (char*)d_ws;
    double* sum1  = (double*)(ws);
    double* ss1   = (double*)(ws + 16384);
    float*  mn1   = (float*)(ws + 32768);
    float*  mx1   = (float*)(ws + 40960);
    float*  stats = (float*)(ws + 49152);
    double* sum2  = (double*)(ws + 49280);

    k_stats<<<NB, BS, 0, stream>>>(tgt, n, sum1, ss1, mn1, mx1);
    k_finalize_stats<<<1, TBS, 0, stream>>>(sum1, ss1, mn1, mx1, (long long)n, stats);
    k_loss<<<NB, BS, 0, stream>>>(inp, tgt, n, stats, sum2);
    k_final<<<1, TBS, 0, stream>>>(sum2, (long long)n, (float*)d_out);
}

// Round 8
// 44.115 us; speedup vs baseline: 1.0642x; 1.0312x over previous
//
#include <hip/hip_runtime.h>
#include <math.h>

#define BS 256          // big-kernel block size
#define NB 2048         // big-kernel grid (8 blocks/CU on 256 CUs)
#define NWAVES (BS / 64)
#define TBS 1024        // fold-kernel block size
#define TNW (TBS / 64)

// ---------- wave reduction helpers ----------
__device__ inline double wred_sum(double v) {
#pragma unroll
    for (int o = 32; o > 0; o >>= 1) v += __shfl_down(v, o, 64);
    return v;
}
__device__ inline float wred_min(float v) {
#pragma unroll
    for (int o = 32; o > 0; o >>= 1) v = fminf(v, __shfl_down(v, o, 64));
    return v;
}
__device__ inline float wred_max(float v) {
#pragma unroll
    for (int o = 32; o > 0; o >>= 1) v = fmaxf(v, __shfl_down(v, o, 64));
    return v;
}

__device__ inline void acc_stats(float4 v, double& s, double& ss, float& mn, float& mx) {
    mn = fminf(mn, fminf(fminf(v.x, v.y), fminf(v.z, v.w)));
    mx = fmaxf(mx, fmaxf(fmaxf(v.x, v.y), fmaxf(v.z, v.w)));
    s += (double)v.x + (double)v.y + (double)v.z + (double)v.w;
    ss += (double)v.x * v.x + (double)v.y * v.y
        + (double)v.z * v.z + (double)v.w * v.w;
}

// ---------- pass 1: per-block {sum, sumsq, min, max} over targets ----------
// CONTIGUOUS per-block chunk: block b owns float4s [b*cpb, (b+1)*cpb).
// Waves advance 4 KB per step inside the chunk — no 4 MB stride hops.
__global__ void __launch_bounds__(BS) k_stats(
        const float* __restrict__ t, int n,
        double* __restrict__ bsum, double* __restrict__ bss,
        float* __restrict__ bmn, float* __restrict__ bmx) {
    int n4 = n >> 2;
    int cpb = (n4 + NB - 1) / NB;             // float4s per block
    int start = blockIdx.x * cpb;
    int end = min(start + cpb, n4);
    const float4* t4 = (const float4*)t;

    double s = 0.0, ss = 0.0;
    float mn = 3.4e38f, mx = -3.4e38f;
    int i = start + threadIdx.x;
    for (; i + 3 * BS < end; i += 4 * BS) {   // 4 loads in flight, 4 KB apart
        float4 a = t4[i];
        float4 b = t4[i + BS];
        float4 c = t4[i + 2 * BS];
        float4 d = t4[i + 3 * BS];
        acc_stats(a, s, ss, mn, mx);
        acc_stats(b, s, ss, mn, mx);
        acc_stats(c, s, ss, mn, mx);
        acc_stats(d, s, ss, mn, mx);
    }
    for (; i < end; i += BS) {
        float4 a = t4[i];
        acc_stats(a, s, ss, mn, mx);
    }
    if (blockIdx.x == 0 && threadIdx.x == 0) {  // scalar tail (n % 4)
        for (int j = (n4 << 2); j < n; j++) {
            float v = t[j];
            mn = fminf(mn, v); mx = fmaxf(mx, v);
            s += v; ss += (double)v * v;
        }
    }

    s = wred_sum(s); ss = wred_sum(ss); mn = wred_min(mn); mx = wred_max(mx);

    __shared__ double sh_s[NWAVES], sh_ss[NWAVES];
    __shared__ float sh_mn[NWAVES], sh_mx[NWAVES];
    int wid = threadIdx.x >> 6, lane = threadIdx.x & 63;
    if (lane == 0) { sh_s[wid] = s; sh_ss[wid] = ss; sh_mn[wid] = mn; sh_mx[wid] = mx; }
    __syncthreads();
    if (threadIdx.x == 0) {
        double S = sh_s[0], SS = sh_ss[0];
        float MN = sh_mn[0], MX = sh_mx[0];
        for (int k = 1; k < NWAVES; k++) {
            S += sh_s[k]; SS += sh_ss[k];
            MN = fminf(MN, sh_mn[k]); MX = fmaxf(MX, sh_mx[k]);
        }
        bsum[blockIdx.x] = S; bss[blockIdx.x] = SS;
        bmn[blockIdx.x] = MN; bmx[blockIdx.x] = MX;
    }
}

// ---------- pass 2: fold block partials -> piecewise-weight constants ----------
__global__ void __launch_bounds__(TBS) k_finalize_stats(
        const double* __restrict__ bsum, const double* __restrict__ bss,
        const float* __restrict__ bmn, const float* __restrict__ bmx,
        long long n, float* __restrict__ stats) {
    double s = 0.0, ss = 0.0;
    float mn = 3.4e38f, mx = -3.4e38f;
    for (int i = threadIdx.x; i < NB; i += TBS) {
        s += bsum[i]; ss += bss[i];
        mn = fminf(mn, bmn[i]); mx = fmaxf(mx, bmx[i]);
    }
    s = wred_sum(s); ss = wred_sum(ss); mn = wred_min(mn); mx = wred_max(mx);

    __shared__ double sh_s[TNW], sh_ss[TNW];
    __shared__ float sh_mn[TNW], sh_mx[TNW];
    int wid = threadIdx.x >> 6, lane = threadIdx.x & 63;
    if (lane == 0) { sh_s[wid] = s; sh_ss[wid] = ss; sh_mn[wid] = mn; sh_mx[wid] = mx; }
    __syncthreads();
    if (threadIdx.x == 0) {
        double S = sh_s[0], SS = sh_ss[0];
        float MN = sh_mn[0], MX = sh_mx[0];
        for (int i = 1; i < TNW; i++) {
            S += sh_s[i]; SS += sh_ss[i];
            MN = fminf(MN, sh_mn[i]); MX = fmaxf(MX, sh_mx[i]);
        }
        double dn = (double)n;
        double mean = S / dn;
        double var = (SS - S * S / dn) / (dn - 1.0);   // ddof=1
        double sd = sqrt(var);
        float gmin = MN, gmax = MX;
        float m1 = (float)(mean + sd);
        float m2 = (float)(mean + 3.0 * sd);
        stats[0] = gmin;
        stats[1] = m1;
        stats[2] = m2;
        stats[3] = gmax;
        stats[4] = 0.2f / (m1 - gmin);   // low slope
        stats[5] = 0.5f / (m2 - m1);     // mid slope
        stats[6] = 0.3f / (gmax - m2);   // high slope
    }
}

// ---------- pass 3: weighted L1 partial sums (contiguous chunks) ----------
__device__ inline float welem(float g, float x, float gmin, float m1, float m2,
                              float sl, float sm, float shv) {
    float d = fabsf(g - x);
    float wlo = (g - gmin) * sl;
    float wmi = fmaf(g - m1, sm, 0.2f);
    float whi = fmaf(g - m2, shv, 0.7f);
    float w = (g <= m1) ? wlo : ((g <= m2) ? wmi : whi);
    return d * w;
}

__device__ inline float wquad(float4 tv, float4 xv, float gmin, float m1,
                              float m2, float sl, float sm, float shv) {
    return welem(tv.x, xv.x, gmin, m1, m2, sl, sm, shv)
         + welem(tv.y, xv.y, gmin, m1, m2, sl, sm, shv)
         + welem(tv.z, xv.z, gmin, m1, m2, sl, sm, shv)
         + welem(tv.w, xv.w, gmin, m1, m2, sl, sm, shv);
}

__global__ void __launch_bounds__(BS) k_loss(
        const float* __restrict__ x, const float* __restrict__ t, int n,
        const float* __restrict__ stats, double* __restrict__ bsum) {
    float gmin = stats[0], m1 = stats[1], m2 = stats[2];
    float sl = stats[4], sm = stats[5], shv = stats[6];
    int n4 = n >> 2;
    int cpb = (n4 + NB - 1) / NB;
    int start = blockIdx.x * cpb;
    int end = min(start + cpb, n4);
    const float4* x4 = (const float4*)x;
    const float4* t4 = (const float4*)t;

    double acc = 0.0;
    int i = start + threadIdx.x;
    for (; i + 3 * BS < end; i += 4 * BS) {   // 8 loads in flight (4 t + 4 x)
        float4 ta = t4[i];            float4 xa = x4[i];
        float4 tb = t4[i + BS];       float4 xb = x4[i + BS];
        float4 tc = t4[i + 2 * BS];   float4 xc = x4[i + 2 * BS];
        float4 td = t4[i + 3 * BS];   float4 xd = x4[i + 3 * BS];
        float e0 = wquad(ta, xa, gmin, m1, m2, sl, sm, shv);
        float e1 = wquad(tb, xb, gmin, m1, m2, sl, sm, shv);
        float e2 = wquad(tc, xc, gmin, m1, m2, sl, sm, shv);
        float e3 = wquad(td, xd, gmin, m1, m2, sl, sm, shv);
        acc += (double)(e0 + e1) + (double)(e2 + e3);
    }
    for (; i < end; i += BS) {
        float4 tv = t4[i], xv = x4[i];
        acc += (double)wquad(tv, xv, gmin, m1, m2, sl, sm, shv);
    }
    if (blockIdx.x == 0 && threadIdx.x == 0) {  // scalar tail (n % 4)
        for (int j = (n4 << 2); j < n; j++)
            acc += (double)welem(t[j], x[j], gmin, m1, m2, sl, sm, shv);
    }

    acc = wred_sum(acc);
    __shared__ double sh_s[NWAVES];
    int wid = threadIdx.x >> 6, lane = threadIdx.x & 63;
    if (lane == 0) sh_s[wid] = acc;
    __syncthreads();
    if (threadIdx.x == 0) {
        double S = sh_s[0];
        for (int k = 1; k < NWAVES; k++) S += sh_s[k];
        bsum[blockIdx.x] = S;
    }
}

// ---------- pass 4: final mean ----------
__global__ void __launch_bounds__(TBS) k_final(
        const double* __restrict__ bsum, long long n, float* __restrict__ out) {
    double s = 0.0;
    for (int i = threadIdx.x; i < NB; i += TBS) s += bsum[i];
    s = wred_sum(s);
    __shared__ double sh_s[TNW];
    int wid = threadIdx.x >> 6, lane = threadIdx.x & 63;
    if (lane == 0) sh_s[wid] = s;
    __syncthreads();
    if (threadIdx.x == 0) {
        double S = sh_s[0];
        for (int i = 1; i < TNW; i++) S += sh_s[i];
        out[0] = (float)(S / (double)n);
    }
}

extern "C" void kernel_launch(void* const* d_in, const int* in_sizes, int n_in,
                              void* d_out, int out_size, void* d_ws, size_t ws_size,
                              hipStream_t stream) {
    const float* inp = (const float*)d_in[0];
    const float* tgt = (const float*)d_in[1];
    int n = in_sizes[0];

    // workspace layout (bytes); plain stores -> no init needed:
    //   [0,      16384) double sum1[NB]
    //   [16384,  32768) double ss1[NB]
    //   [32768,  40960) float  mn1[NB]
    //   [40960,  49152) float  mx1[NB]
    //   [49152,  49216) float  stats[16]
    //   [49280,  65664) double sum2[NB]
    char* ws = (char*)d_ws;
    double* sum1  = (double*)(ws);
    double* ss1   = (double*)(ws + 16384);
    float*  mn1   = (float*)(ws + 32768);
    float*  mx1   = (float*)(ws + 40960);
    float*  stats = (float*)(ws + 49152);
    double* sum2  = (double*)(ws + 49280);

    k_stats<<<NB, BS, 0, stream>>>(tgt, n, sum1, ss1, mn1, mx1);
    k_finalize_stats<<<1, TBS, 0, stream>>>(sum1, ss1, mn1, mx1, (long long)n, stats);
    k_loss<<<NB, BS, 0, stream>>>(inp, tgt, n, stats, sum2);
    k_final<<<1, TBS, 0, stream>>>(sum2, (long long)n, (float*)d_out);
}

// Round 9
// 43.857 us; speedup vs baseline: 1.0705x; 1.0059x over previous
//
#include <hip/hip_runtime.h>
#include <math.h>

#define BS 256          // big-kernel block size
#define NB 2048         // big-kernel grid (8 blocks/CU on 256 CUs)
#define NWAVES (BS / 64)
#define TBS 1024        // fold-kernel block size
#define TNW (TBS / 64)
#define CPB 2048        // float4s per block chunk when n4 == NB*CPB (4096^2 case)

// ---------- wave reduction helpers ----------
__device__ inline double wred_sum(double v) {
#pragma unroll
    for (int o = 32; o > 0; o >>= 1) v += __shfl_down(v, o, 64);
    return v;
}
__device__ inline float wred_min(float v) {
#pragma unroll
    for (int o = 32; o > 0; o >>= 1) v = fminf(v, __shfl_down(v, o, 64));
    return v;
}
__device__ inline float wred_max(float v) {
#pragma unroll
    for (int o = 32; o > 0; o >>= 1) v = fmaxf(v, __shfl_down(v, o, 64));
    return v;
}

__device__ inline void acc_stats(float4 v, double& s, double& ss, float& mn, float& mx) {
    mn = fminf(mn, fminf(fminf(v.x, v.y), fminf(v.z, v.w)));
    mx = fmaxf(mx, fmaxf(fmaxf(v.x, v.y), fmaxf(v.z, v.w)));
    s += (double)v.x + (double)v.y + (double)v.z + (double)v.w;
    ss += (double)v.x * v.x + (double)v.y * v.y
        + (double)v.z * v.z + (double)v.w * v.w;
}

// direct global -> LDS copy, 16 B per lane; lds base must be wave-uniform
__device__ inline void gload16(const float4* g, float4* s) {
    __builtin_amdgcn_global_load_lds(
        (const __attribute__((address_space(1))) void*)g,
        (__attribute__((address_space(3))) void*)s, 16, 0, 0);
}

// ---------- pass 1: per-block {sum, sumsq, min, max} over targets ----------
__global__ void __launch_bounds__(BS) k_stats(
        const float* __restrict__ t, int n,
        double* __restrict__ bsum, double* __restrict__ bss,
        float* __restrict__ bmn, float* __restrict__ bmx) {
    int n4 = n >> 2;
    int cpb = (n4 + NB - 1) / NB;             // float4s per block
    int start = blockIdx.x * cpb;
    int end = min(start + cpb, n4);
    const float4* t4 = (const float4*)t;

    double s = 0.0, ss = 0.0;
    float mn = 3.4e38f, mx = -3.4e38f;
    int i = start + threadIdx.x;
    for (; i + 3 * BS < end; i += 4 * BS) {   // 4 loads in flight, 4 KB apart
        float4 a = t4[i];
        float4 b = t4[i + BS];
        float4 c = t4[i + 2 * BS];
        float4 d = t4[i + 3 * BS];
        acc_stats(a, s, ss, mn, mx);
        acc_stats(b, s, ss, mn, mx);
        acc_stats(c, s, ss, mn, mx);
        acc_stats(d, s, ss, mn, mx);
    }
    for (; i < end; i += BS) {
        float4 a = t4[i];
        acc_stats(a, s, ss, mn, mx);
    }
    if (blockIdx.x == 0 && threadIdx.x == 0) {  // scalar tail (n % 4)
        for (int j = (n4 << 2); j < n; j++) {
            float v = t[j];
            mn = fminf(mn, v); mx = fmaxf(mx, v);
            s += v; ss += (double)v * v;
        }
    }

    s = wred_sum(s); ss = wred_sum(ss); mn = wred_min(mn); mx = wred_max(mx);

    __shared__ double sh_s[NWAVES], sh_ss[NWAVES];
    __shared__ float sh_mn[NWAVES], sh_mx[NWAVES];
    int wid = threadIdx.x >> 6, lane = threadIdx.x & 63;
    if (lane == 0) { sh_s[wid] = s; sh_ss[wid] = ss; sh_mn[wid] = mn; sh_mx[wid] = mx; }
    __syncthreads();
    if (threadIdx.x == 0) {
        double S = sh_s[0], SS = sh_ss[0];
        float MN = sh_mn[0], MX = sh_mx[0];
        for (int k = 1; k < NWAVES; k++) {
            S += sh_s[k]; SS += sh_ss[k];
            MN = fminf(MN, sh_mn[k]); MX = fmaxf(MX, sh_mx[k]);
        }
        bsum[blockIdx.x] = S; bss[blockIdx.x] = SS;
        bmn[blockIdx.x] = MN; bmx[blockIdx.x] = MX;
    }
}

// ---------- pass 2: fold block partials -> piecewise-weight constants ----------
__global__ void __launch_bounds__(TBS) k_finalize_stats(
        const double* __restrict__ bsum, const double* __restrict__ bss,
        const float* __restrict__ bmn, const float* __restrict__ bmx,
        long long n, float* __restrict__ stats) {
    double s = 0.0, ss = 0.0;
    float mn = 3.4e38f, mx = -3.4e38f;
    for (int i = threadIdx.x; i < NB; i += TBS) {
        s += bsum[i]; ss += bss[i];
        mn = fminf(mn, bmn[i]); mx = fmaxf(mx, bmx[i]);
    }
    s = wred_sum(s); ss = wred_sum(ss); mn = wred_min(mn); mx = wred_max(mx);

    __shared__ double sh_s[TNW], sh_ss[TNW];
    __shared__ float sh_mn[TNW], sh_mx[TNW];
    int wid = threadIdx.x >> 6, lane = threadIdx.x & 63;
    if (lane == 0) { sh_s[wid] = s; sh_ss[wid] = ss; sh_mn[wid] = mn; sh_mx[wid] = mx; }
    __syncthreads();
    if (threadIdx.x == 0) {
        double S = sh_s[0], SS = sh_ss[0];
        float MN = sh_mn[0], MX = sh_mx[0];
        for (int i = 1; i < TNW; i++) {
            S += sh_s[i]; SS += sh_ss[i];
            MN = fminf(MN, sh_mn[i]); MX = fmaxf(MX, sh_mx[i]);
        }
        double dn = (double)n;
        double mean = S / dn;
        double var = (SS - S * S / dn) / (dn - 1.0);   // ddof=1
        double sd = sqrt(var);
        float gmin = MN, gmax = MX;
        float m1 = (float)(mean + sd);
        float m2 = (float)(mean + 3.0 * sd);
        stats[0] = gmin;
        stats[1] = m1;
        stats[2] = m2;
        stats[3] = gmax;
        stats[4] = 0.2f / (m1 - gmin);   // low slope
        stats[5] = 0.5f / (m2 - m1);     // mid slope
        stats[6] = 0.3f / (gmax - m2);   // high slope
    }
}

// ---------- pass 3: weighted L1, LDS-staged single-stream bursts ----------
__device__ inline float welem(float g, float x, float gmin, float m1, float m2,
                              float sl, float sm, float shv) {
    float d = fabsf(g - x);
    float wlo = (g - gmin) * sl;
    float wmi = fmaf(g - m1, sm, 0.2f);
    float whi = fmaf(g - m2, shv, 0.7f);
    float w = (g <= m1) ? wlo : ((g <= m2) ? wmi : whi);
    return d * w;
}

__device__ inline float wquad(float4 tv, float4 xv, float gmin, float m1,
                              float m2, float sl, float sm, float shv) {
    return welem(tv.x, xv.x, gmin, m1, m2, sl, sm, shv)
         + welem(tv.y, xv.y, gmin, m1, m2, sl, sm, shv)
         + welem(tv.z, xv.z, gmin, m1, m2, sl, sm, shv)
         + welem(tv.w, xv.w, gmin, m1, m2, sl, sm, shv);
}

__global__ void __launch_bounds__(BS) k_loss(
        const float* __restrict__ x, const float* __restrict__ t, int n,
        const float* __restrict__ stats, double* __restrict__ bsum) {
    float gmin = stats[0], m1 = stats[1], m2 = stats[2];
    float sl = stats[4], sm = stats[5], shv = stats[6];
    int n4 = n >> 2;
    int cpb = (n4 + NB - 1) / NB;
    int start = blockIdx.x * cpb;
    int end = min(start + cpb, n4);
    int len = end - start;
    const float4* x4 = (const float4*)x;
    const float4* t4 = (const float4*)t;

    __shared__ float4 st[CPB];        // 32 KB t-chunk stage
    double acc = 0.0;

    if (cpb == CPB && len == CPB) {
        // --- phase A: single-stream burst t-chunk -> LDS (no VGPR round-trip)
        int w = threadIdx.x >> 6, l = threadIdx.x & 63;
        const float4* gt = t4 + start;
#pragma unroll
        for (int j = 0; j < CPB / BS; ++j) {
            int off = j * BS + w * 64;            // wave-uniform float4 offset
            gload16(gt + off + l, st + off);      // HW adds lane*16 to LDS dest
        }
        asm volatile("s_waitcnt vmcnt(0)" ::: "memory");
        __syncthreads();

        // --- phase B: single-stream burst x-chunk, combine vs LDS ---
#pragma unroll
        for (int j = 0; j < CPB / BS; j += 4) {
            int b = j * BS + threadIdx.x;
            float4 xa = x4[start + b];
            float4 xb = x4[start + b + BS];
            float4 xc = x4[start + b + 2 * BS];
            float4 xd = x4[start + b + 3 * BS];
            float4 ta = st[b];
            float4 tb = st[b + BS];
            float4 tc = st[b + 2 * BS];
            float4 td = st[b + 3 * BS];
            float e0 = wquad(ta, xa, gmin, m1, m2, sl, sm, shv);
            float e1 = wquad(tb, xb, gmin, m1, m2, sl, sm, shv);
            float e2 = wquad(tc, xc, gmin, m1, m2, sl, sm, shv);
            float e3 = wquad(td, xd, gmin, m1, m2, sl, sm, shv);
            acc += (double)(e0 + e1) + (double)(e2 + e3);
        }
    } else {
        // fallback: ragged chunk (generic shapes)
        for (int i = start + threadIdx.x; i < end; i += BS) {
            float4 tv = t4[i], xv = x4[i];
            acc += (double)wquad(tv, xv, gmin, m1, m2, sl, sm, shv);
        }
    }
    if (blockIdx.x == 0 && threadIdx.x == 0) {  // scalar tail (n % 4)
        for (int j = (n4 << 2); j < n; j++)
            acc += (double)welem(t[j], x[j], gmin, m1, m2, sl, sm, shv);
    }

    acc = wred_sum(acc);
    __shared__ double sh_s[NWAVES];
    int wid = threadIdx.x >> 6, lane = threadIdx.x & 63;
    if (lane == 0) sh_s[wid] = acc;
    __syncthreads();
    if (threadIdx.x == 0) {
        double S = sh_s[0];
        for (int k = 1; k < NWAVES; k++) S += sh_s[k];
        bsum[blockIdx.x] = S;
    }
}

// ---------- pass 4: final mean ----------
__global__ void __launch_bounds__(TBS) k_final(
        const double* __restrict__ bsum, long long n, float* __restrict__ out) {
    double s = 0.0;
    for (int i = threadIdx.x; i < NB; i += TBS) s += bsum[i];
    s = wred_sum(s);
    __shared__ double sh_s[TNW];
    int wid = threadIdx.x >> 6, lane = threadIdx.x & 63;
    if (lane == 0) sh_s[wid] = s;
    __syncthreads();
    if (threadIdx.x == 0) {
        double S = sh_s[0];
        for (int i = 1; i < TNW; i++) S += sh_s[i];
        out[0] = (float)(S / (double)n);
    }
}

extern "C" void kernel_launch(void* const* d_in, const int* in_sizes, int n_in,
                              void* d_out, int out_size, void* d_ws, size_t ws_size,
                              hipStream_t stream) {
    const float* inp = (const float*)d_in[0];
    const float* tgt = (const float*)d_in[1];
    int n = in_sizes[0];

    // workspace layout (bytes); plain stores -> no init needed:
    //   [0,      16384) double sum1[NB]
    //   [16384,  32768) double ss1[NB]
    //   [32768,  40960) float  mn1[NB]
    //   [40960,  49152) float  mx1[NB]
    //   [49152,  49216) float  stats[16]
    //   [49280,  65664) double sum2[NB]
    char* ws = (char*)d_ws;
    double* sum1  = (double*)(ws);
    double* ss1   = (double*)(ws + 16384);
    float*  mn1   = (float*)(ws + 32768);
    float*  mx1   = (float*)(ws + 40960);
    float*  stats = (float*)(ws + 49152);
    double* sum2  = (double*)(ws + 49280);

    k_stats<<<NB, BS, 0, stream>>>(tgt, n, sum1, ss1, mn1, mx1);
    k_finalize_stats<<<1, TBS, 0, stream>>>(sum1, ss1, mn1, mx1, (long long)n, stats);
    k_loss<<<NB, BS, 0, stream>>>(inp, tgt, n, stats, sum2);
    k_final<<<1, TBS, 0, stream>>>(sum2, (long long)n, (float*)d_out);
}